// Round 1
// baseline (3263.046 us; speedup 1.0000x reference)
//
#include <hip/hip_runtime.h>
#include <math.h>

#define BT 32768
#define TT 20
#define NA 4
#define DD 8
#define HH 64
#define G3 192   // 3*H

__device__ __forceinline__ float fsig(float x) { return 1.0f / (1.0f + __expf(-x)); }
__device__ __forceinline__ float ftanh(float x) {
    // tanh via exp(-2|x|): e in (0,1], no overflow, no inf/inf NaN
    float e = __expf(-2.0f * fabsf(x));
    float t = (1.0f - e) / (1.0f + e);
    return copysignf(t, x);
}

// Transpose Wh [N][H][3H] -> WhT [N][3H][H], Wi [N][D][3H] -> WiT [N][3H][D]
__global__ void wtrans_kernel(const float* __restrict__ Wi, const float* __restrict__ Wh,
                              float* __restrict__ WiT, float* __restrict__ WhT) {
    const int n  = blockIdx.x / G3;
    const int gj = blockIdx.x % G3;
    const int k  = threadIdx.x;
    WhT[(n * G3 + gj) * HH + k] = Wh[(n * HH + k) * G3 + gj];
    if (k < DD) WiT[(n * G3 + gj) * DD + k] = Wi[(n * DD + k) * G3 + gj];
}

// GRU over T steps. One thread per (batch, agent). h kept in VGPRs (all indices
// compile-time); runtime-indexed h_new[j] handled via a PRIVATE LDS column
// scr[j][tid] (lane-consecutive -> conflict-free; thread-private -> NO barriers).
// WhT/WiT/bh reads are wave-uniform -> scalarized to s_load (SMEM pipe).
__global__ __launch_bounds__(256, 2)
void gru_kernel(const float* __restrict__ x, const float* __restrict__ WiT,
                const float* __restrict__ WhT, const float* __restrict__ bh,
                float* __restrict__ feat) {
    __shared__ float scr[HH][256];  // exactly 64 KB -> 2 blocks/CU
    const int tid = threadIdx.x;
    const int n   = blockIdx.y;
    const int b   = blockIdx.x * 256 + tid;

    const float* __restrict__ xp  = x + (size_t)b * (TT * NA * DD) + n * DD;
    const float* __restrict__ wi  = WiT + (size_t)n * G3 * DD;
    const float* __restrict__ wh  = WhT + (size_t)n * G3 * HH;
    const float* __restrict__ bhn = bh + (size_t)n * G3;

    float h[HH];
#pragma unroll
    for (int k = 0; k < HH; k++) { h[k] = 0.0f; scr[k][tid] = 0.0f; }

    for (int t = 0; t < TT; t++) {
        const float4 xa = *(const float4*)(xp + t * (NA * DD));
        const float4 xb = *(const float4*)(xp + t * (NA * DD) + 4);

        for (int j = 0; j < HH; j++) {
            const float4* __restrict__ wr = (const float4*)(wh + (size_t)j * HH);
            const float4* __restrict__ wz = (const float4*)(wh + (size_t)(HH + j) * HH);
            const float4* __restrict__ wn = (const float4*)(wh + (size_t)(2 * HH + j) * HH);
            float r0 = 0.f, r1 = 0.f, z0 = 0.f, z1 = 0.f, n0 = 0.f, n1 = 0.f;
#pragma unroll
            for (int kk = 0; kk < 16; kk += 2) {
                const float4 a0 = wr[kk], a1 = wr[kk + 1];
                const float4 c0 = wz[kk], c1 = wz[kk + 1];
                const float4 d0 = wn[kk], d1 = wn[kk + 1];
                r0 = fmaf(h[4*kk+0], a0.x, fmaf(h[4*kk+1], a0.y, fmaf(h[4*kk+2], a0.z, fmaf(h[4*kk+3], a0.w, r0))));
                r1 = fmaf(h[4*kk+4], a1.x, fmaf(h[4*kk+5], a1.y, fmaf(h[4*kk+6], a1.z, fmaf(h[4*kk+7], a1.w, r1))));
                z0 = fmaf(h[4*kk+0], c0.x, fmaf(h[4*kk+1], c0.y, fmaf(h[4*kk+2], c0.z, fmaf(h[4*kk+3], c0.w, z0))));
                z1 = fmaf(h[4*kk+4], c1.x, fmaf(h[4*kk+5], c1.y, fmaf(h[4*kk+6], c1.z, fmaf(h[4*kk+7], c1.w, z1))));
                n0 = fmaf(h[4*kk+0], d0.x, fmaf(h[4*kk+1], d0.y, fmaf(h[4*kk+2], d0.z, fmaf(h[4*kk+3], d0.w, n0))));
                n1 = fmaf(h[4*kk+4], d1.x, fmaf(h[4*kk+5], d1.y, fmaf(h[4*kk+6], d1.z, fmaf(h[4*kk+7], d1.w, n1))));
            }
            const float4* __restrict__ vr = (const float4*)(wi + (size_t)j * DD);
            const float4* __restrict__ vz = (const float4*)(wi + (size_t)(HH + j) * DD);
            const float4* __restrict__ vn = (const float4*)(wi + (size_t)(2 * HH + j) * DD);
            const float4 p0 = vr[0], p1 = vr[1];
            const float4 q0 = vz[0], q1 = vz[1];
            const float4 s0 = vn[0], s1 = vn[1];
            float ir  = xa.x*p0.x + xa.y*p0.y + xa.z*p0.z + xa.w*p0.w
                      + xb.x*p1.x + xb.y*p1.y + xb.z*p1.z + xb.w*p1.w;
            float iz  = xa.x*q0.x + xa.y*q0.y + xa.z*q0.z + xa.w*q0.w
                      + xb.x*q1.x + xb.y*q1.y + xb.z*q1.z + xb.w*q1.w;
            float inn = xa.x*s0.x + xa.y*s0.y + xa.z*s0.z + xa.w*s0.w
                      + xb.x*s1.x + xb.y*s1.y + xb.z*s1.z + xb.w*s1.w;

            const float rpre = (r0 + r1) + ir + bhn[j];
            const float zpre = (z0 + z1) + iz + bhn[HH + j];
            const float hn   = (n0 + n1) + bhn[2 * HH + j];
            const float hold = scr[j][tid];           // old h[j] (runtime j via LDS)
            const float rg = fsig(rpre);
            const float zg = fsig(zpre);
            const float ng = ftanh(inn + rg * hn);
            scr[j][tid] = (1.0f - zg) * ng + zg * hold;
        }
#pragma unroll
        for (int k = 0; k < HH; k++) h[k] = scr[k][tid];  // refresh register copy
    }

    float* __restrict__ fp = feat + (size_t)b * (NA * HH) + n * HH;
#pragma unroll
    for (int k = 0; k < HH; k += 4)
        *(float4*)(fp + k) = make_float4(h[k], h[k + 1], h[k + 2], h[k + 3]);
}

// Fused MLP: feat[B,256] -> relu(W0)+b0 -> relu(W1)+b1 -> Wout+bout -> out[B,8]
// 64 batch rows/block, 256 threads: thread = (bl = tid>>2, quarter q = tid&3).
// h1/h2 staged TRANSPOSED [j][bl] in LDS -> conflict-free stage-2/3 reads.
__global__ __launch_bounds__(256, 2)
void mlp_kernel(const float* __restrict__ feat, const float* __restrict__ W0,
                const float* __restrict__ b0, const float* __restrict__ W1,
                const float* __restrict__ b1, const float* __restrict__ Wout,
                const float* __restrict__ bout, float* __restrict__ out) {
    __shared__ float hbuf[256 * 64];  // [j][bl], exactly 64 KB
    const int tid = threadIdx.x;
    const int bl  = tid >> 2;
    const int q   = tid & 3;
    const int bg  = blockIdx.x * 64 + bl;
    const float* __restrict__ fr = feat + (size_t)bg * 256;

    // stage 1: h1[bl][q*64 .. q*64+63]
    float acc[64];
#pragma unroll
    for (int i = 0; i < 64; i++) acc[i] = b0[q * 64 + i];
    for (int k = 0; k < 256; k++) {
        const float f = fr[k];
        const float4* __restrict__ w = (const float4*)(W0 + (size_t)k * 256 + q * 64);
#pragma unroll
        for (int i = 0; i < 16; i++) {
            const float4 wv = w[i];
            acc[4*i+0] = fmaf(f, wv.x, acc[4*i+0]);
            acc[4*i+1] = fmaf(f, wv.y, acc[4*i+1]);
            acc[4*i+2] = fmaf(f, wv.z, acc[4*i+2]);
            acc[4*i+3] = fmaf(f, wv.w, acc[4*i+3]);
        }
    }
#pragma unroll
    for (int i = 0; i < 64; i++) {
        const float v = acc[i];
        hbuf[(q * 64 + i) * 64 + bl] = v > 0.f ? v : 0.f;
    }
    __syncthreads();

    // stage 2: h2[bl][q*32 .. q*32+31]
    float a2[32];
#pragma unroll
    for (int i = 0; i < 32; i++) a2[i] = b1[q * 32 + i];
    for (int k = 0; k < 256; k++) {
        const float f = hbuf[k * 64 + bl];
        const float4* __restrict__ w = (const float4*)(W1 + (size_t)k * 128 + q * 32);
#pragma unroll
        for (int i = 0; i < 8; i++) {
            const float4 wv = w[i];
            a2[4*i+0] = fmaf(f, wv.x, a2[4*i+0]);
            a2[4*i+1] = fmaf(f, wv.y, a2[4*i+1]);
            a2[4*i+2] = fmaf(f, wv.z, a2[4*i+2]);
            a2[4*i+3] = fmaf(f, wv.w, a2[4*i+3]);
        }
    }
    __syncthreads();  // all stage-2 reads done before overwrite
#pragma unroll
    for (int i = 0; i < 32; i++) {
        const float v = a2[i];
        hbuf[(q * 32 + i) * 64 + bl] = v > 0.f ? v : 0.f;
    }
    __syncthreads();

    // stage 3: 2 outputs per thread
    float o0 = bout[2 * q], o1 = bout[2 * q + 1];
    for (int k = 0; k < 128; k++) {
        const float f = hbuf[k * 64 + bl];
        const float2 wv = *(const float2*)(Wout + k * 8 + 2 * q);
        o0 = fmaf(f, wv.x, o0);
        o1 = fmaf(f, wv.y, o1);
    }
    *(float2*)(out + (size_t)bg * 8 + 2 * q) = make_float2(o0, o1);
}

extern "C" void kernel_launch(void* const* d_in, const int* in_sizes, int n_in,
                              void* d_out, int out_size, void* d_ws, size_t ws_size,
                              hipStream_t stream) {
    const float* x    = (const float*)d_in[0];
    const float* Wi   = (const float*)d_in[1];
    const float* Wh   = (const float*)d_in[2];
    const float* bh   = (const float*)d_in[3];
    const float* W0   = (const float*)d_in[4];
    const float* b0   = (const float*)d_in[5];
    const float* W1   = (const float*)d_in[6];
    const float* b1   = (const float*)d_in[7];
    const float* Wout = (const float*)d_in[8];
    const float* bout = (const float*)d_in[9];
    float* out = (float*)d_out;

    float* ws   = (float*)d_ws;
    float* feat = ws;                               // B * 256 floats
    float* WhT  = ws + (size_t)BT * (NA * HH);      // N*192*64
    float* WiT  = WhT + (size_t)NA * G3 * HH;       // N*192*8

    wtrans_kernel<<<NA * G3, 64, 0, stream>>>(Wi, Wh, WiT, WhT);
    gru_kernel<<<dim3(BT / 256, NA), 256, 0, stream>>>(x, WiT, WhT, bh, feat);
    mlp_kernel<<<BT / 64, 256, 0, stream>>>(feat, W0, b0, W1, b1, Wout, bout, out);
}

// Round 2
// 3213.037 us; speedup vs baseline: 1.0156x; 1.0156x over previous
//
#include <hip/hip_runtime.h>
#include <math.h>

#define BT 32768
#define TT 20
#define NA 4
#define DD 8
#define HH 64
#define G3 192   // 3*H

__device__ __forceinline__ float fsig(float x) { return 1.0f / (1.0f + __expf(-x)); }
__device__ __forceinline__ float ftanh(float x) {
    // tanh via exp(-2|x|): e in (0,1], no overflow, no inf/inf NaN
    float e = __expf(-2.0f * fabsf(x));
    float t = (1.0f - e) / (1.0f + e);
    return copysignf(t, x);
}

// Transpose Wh [N][H][3H] -> WhT [N][3H][H], Wi [N][D][3H] -> WiT [N][3H][D]
__global__ void wtrans_kernel(const float* __restrict__ Wi, const float* __restrict__ Wh,
                              float* __restrict__ WiT, float* __restrict__ WhT) {
    const int n  = blockIdx.x / G3;
    const int gj = blockIdx.x % G3;
    const int k  = threadIdx.x;
    WhT[(n * G3 + gj) * HH + k] = Wh[(n * HH + k) * G3 + gj];
    if (k < DD) WiT[(n * G3 + gj) * DD + k] = Wi[(n * DD + k) * G3 + gj];
}

// GRU over T steps. One thread per (batch, agent). h lives in VGPRs (all dot
// reads compile-time indexed); the runtime-indexed h_new[j] write goes to a
// 256B private SCRATCH array (no LDS at all -> grid-limited 2 waves/SIMD is
// the only occupancy cap; full 256-VGPR budget for load pipelining).
// kk-dot fully unrolled -> weight loads are base+imm-offset (no addr VALU).
__global__ __launch_bounds__(256, 2)
void gru_kernel(const float* __restrict__ x, const float* __restrict__ WiT,
                const float* __restrict__ WhT, const float* __restrict__ bh,
                float* __restrict__ featT) {
    const int tid = threadIdx.x;
    const int n   = blockIdx.y;
    const int b   = blockIdx.x * 256 + tid;

    const float* __restrict__ xp  = x + (size_t)b * (TT * NA * DD) + n * DD;
    const float* __restrict__ wi  = WiT + (size_t)n * G3 * DD;
    const float* __restrict__ wh  = WhT + (size_t)n * G3 * HH;
    const float* __restrict__ bhn = bh + (size_t)n * G3;

    float hpriv[HH];   // scratch-resident (runtime-indexed writes keep it there)
    float h[HH];       // register copy (compile-time indexed reads in the dot)
#pragma unroll
    for (int k = 0; k < HH; k++) h[k] = 0.0f;
#pragma unroll
    for (int k = 0; k < HH; k += 4) *(float4*)&hpriv[k] = make_float4(0.f, 0.f, 0.f, 0.f);

    float4 xa = *(const float4*)(xp);
    float4 xb = *(const float4*)(xp + 4);

    for (int t = 0; t < TT; t++) {
        // prefetch next timestep's x (clamped, branch-free)
        const int tn = (t + 1 < TT) ? (t + 1) : (TT - 1);
        const float4 nxa = *(const float4*)(xp + tn * (NA * DD));
        const float4 nxb = *(const float4*)(xp + tn * (NA * DD) + 4);

#pragma unroll 2
        for (int j = 0; j < HH; j++) {
            const float hold = hpriv[j];              // scratch load, issued early

            // input-side projection for this j (3 gates x D=8)
            const float* __restrict__ vij = wi + (size_t)j * DD;
            const float4 p0 = *(const float4*)(vij);
            const float4 p1 = *(const float4*)(vij + 4);
            const float4 q0 = *(const float4*)(vij + (size_t)HH * DD);
            const float4 q1 = *(const float4*)(vij + (size_t)HH * DD + 4);
            const float4 s0 = *(const float4*)(vij + (size_t)2 * HH * DD);
            const float4 s1 = *(const float4*)(vij + (size_t)2 * HH * DD + 4);

            // hidden-side dots: 3 gate rows of 64, fully unrolled, imm offsets
            const float* __restrict__ wr = wh + (size_t)j * HH;
            const float* __restrict__ wz = wh + (size_t)(HH + j) * HH;
            const float* __restrict__ wn = wh + (size_t)(2 * HH + j) * HH;
            float r0 = 0.f, r1 = 0.f, z0 = 0.f, z1 = 0.f, n0 = 0.f, n1 = 0.f;
#pragma unroll
            for (int kk = 0; kk < 16; kk += 2) {
                const float4 a0 = *(const float4*)(wr + 4 * kk);
                const float4 a1 = *(const float4*)(wr + 4 * kk + 4);
                const float4 c0 = *(const float4*)(wz + 4 * kk);
                const float4 c1 = *(const float4*)(wz + 4 * kk + 4);
                const float4 d0 = *(const float4*)(wn + 4 * kk);
                const float4 d1 = *(const float4*)(wn + 4 * kk + 4);
                r0 = fmaf(h[4*kk+0], a0.x, fmaf(h[4*kk+1], a0.y, fmaf(h[4*kk+2], a0.z, fmaf(h[4*kk+3], a0.w, r0))));
                r1 = fmaf(h[4*kk+4], a1.x, fmaf(h[4*kk+5], a1.y, fmaf(h[4*kk+6], a1.z, fmaf(h[4*kk+7], a1.w, r1))));
                z0 = fmaf(h[4*kk+0], c0.x, fmaf(h[4*kk+1], c0.y, fmaf(h[4*kk+2], c0.z, fmaf(h[4*kk+3], c0.w, z0))));
                z1 = fmaf(h[4*kk+4], c1.x, fmaf(h[4*kk+5], c1.y, fmaf(h[4*kk+6], c1.z, fmaf(h[4*kk+7], c1.w, z1))));
                n0 = fmaf(h[4*kk+0], d0.x, fmaf(h[4*kk+1], d0.y, fmaf(h[4*kk+2], d0.z, fmaf(h[4*kk+3], d0.w, n0))));
                n1 = fmaf(h[4*kk+4], d1.x, fmaf(h[4*kk+5], d1.y, fmaf(h[4*kk+6], d1.z, fmaf(h[4*kk+7], d1.w, n1))));
            }

            float ir  = xa.x*p0.x + xa.y*p0.y + xa.z*p0.z + xa.w*p0.w
                      + xb.x*p1.x + xb.y*p1.y + xb.z*p1.z + xb.w*p1.w;
            float iz  = xa.x*q0.x + xa.y*q0.y + xa.z*q0.z + xa.w*q0.w
                      + xb.x*q1.x + xb.y*q1.y + xb.z*q1.z + xb.w*q1.w;
            float inn = xa.x*s0.x + xa.y*s0.y + xa.z*s0.z + xa.w*s0.w
                      + xb.x*s1.x + xb.y*s1.y + xb.z*s1.z + xb.w*s1.w;

            const float* __restrict__ bj = bhn + j;
            const float rpre = (r0 + r1) + ir + bj[0];
            const float zpre = (z0 + z1) + iz + bj[HH];
            const float hn   = (n0 + n1) + bj[2 * HH];
            const float rg = fsig(rpre);
            const float zg = fsig(zpre);
            const float ng = ftanh(inn + rg * hn);
            hpriv[j] = fmaf(zg, hold - ng, ng);       // (1-z)n + z*hold
        }
        // refresh register copy from scratch (compile-time indices, b128 loads)
#pragma unroll
        for (int k = 0; k < HH; k += 4) {
            const float4 v = *(const float4*)&hpriv[k];
            h[k] = v.x; h[k+1] = v.y; h[k+2] = v.z; h[k+3] = v.w;
        }
        xa = nxa; xb = nxb;
    }

    // write feature TRANSPOSED: featT[n*H+k][b] (coalesced across lanes)
#pragma unroll
    for (int k = 0; k < HH; k++)
        featT[(size_t)(n * HH + k) * BT + b] = h[k];
}

// Fused MLP on featT[256][B]: relu(W0)+b0 -> relu(W1)+b1 -> Wout+bout.
// 32 batch rows/block, 256 threads = (bl 0..31, q 0..7); max 32 accs/thread
// (guaranteed register-resident). feat/h1/h2 staged [k][bl] in 32KB LDS:
// addr%32 == bl -> conflict-free (2-way broadcast across the two q per wave).
__global__ __launch_bounds__(256, 4)
void mlp_kernel(const float* __restrict__ featT, const float* __restrict__ W0,
                const float* __restrict__ b0, const float* __restrict__ W1,
                const float* __restrict__ b1, const float* __restrict__ Wout,
                const float* __restrict__ bout, float* __restrict__ out) {
    __shared__ float sf[256 * 32];   // [k][bl], 32KB
    const int tid = threadIdx.x;
    const int bl  = tid & 31;
    const int q   = tid >> 5;        // 0..7
    const int bg  = blockIdx.x * 32;

    // stage feat tile [256][32] (coalesced global reads, linear LDS writes)
    for (int i = tid; i < 256 * 32; i += 256) {
        const int row = i >> 5, col = i & 31;
        sf[i] = featT[(size_t)row * BT + bg + col];
    }
    __syncthreads();

    // stage 1: h1[bl][q*32 .. q*32+31]
    float acc[32];
#pragma unroll
    for (int i = 0; i < 32; i++) acc[i] = b0[q * 32 + i];
    for (int k = 0; k < 256; k++) {
        const float f = sf[k * 32 + bl];
        const float4* __restrict__ w = (const float4*)(W0 + (size_t)k * 256 + q * 32);
#pragma unroll
        for (int i = 0; i < 8; i++) {
            const float4 wv = w[i];
            acc[4*i+0] = fmaf(f, wv.x, acc[4*i+0]);
            acc[4*i+1] = fmaf(f, wv.y, acc[4*i+1]);
            acc[4*i+2] = fmaf(f, wv.z, acc[4*i+2]);
            acc[4*i+3] = fmaf(f, wv.w, acc[4*i+3]);
        }
    }
    __syncthreads();   // all stage-1 reads of sf done before overwrite
#pragma unroll
    for (int i = 0; i < 32; i++) {
        const float v = acc[i];
        sf[(q * 32 + i) * 32 + bl] = v > 0.f ? v : 0.f;
    }
    __syncthreads();

    // stage 2: h2[bl][q*16 .. q*16+15]
    float a2[16];
#pragma unroll
    for (int i = 0; i < 16; i++) a2[i] = b1[q * 16 + i];
    for (int k = 0; k < 256; k++) {
        const float f = sf[k * 32 + bl];
        const float4* __restrict__ w = (const float4*)(W1 + (size_t)k * 128 + q * 16);
#pragma unroll
        for (int i = 0; i < 4; i++) {
            const float4 wv = w[i];
            a2[4*i+0] = fmaf(f, wv.x, a2[4*i+0]);
            a2[4*i+1] = fmaf(f, wv.y, a2[4*i+1]);
            a2[4*i+2] = fmaf(f, wv.z, a2[4*i+2]);
            a2[4*i+3] = fmaf(f, wv.w, a2[4*i+3]);
        }
    }
    __syncthreads();
#pragma unroll
    for (int i = 0; i < 16; i++) {
        const float v = a2[i];
        sf[(q * 16 + i) * 32 + bl] = v > 0.f ? v : 0.f;
    }
    __syncthreads();

    // stage 3: one output per thread (out dim 8 == #q groups)
    float o = bout[q];
    for (int k = 0; k < 128; k++)
        o = fmaf(sf[k * 32 + bl], Wout[k * 8 + q], o);
    out[(size_t)(bg + bl) * 8 + q] = o;
}

extern "C" void kernel_launch(void* const* d_in, const int* in_sizes, int n_in,
                              void* d_out, int out_size, void* d_ws, size_t ws_size,
                              hipStream_t stream) {
    const float* x    = (const float*)d_in[0];
    const float* Wi   = (const float*)d_in[1];
    const float* Wh   = (const float*)d_in[2];
    const float* bh   = (const float*)d_in[3];
    const float* W0   = (const float*)d_in[4];
    const float* b0   = (const float*)d_in[5];
    const float* W1   = (const float*)d_in[6];
    const float* b1   = (const float*)d_in[7];
    const float* Wout = (const float*)d_in[8];
    const float* bout = (const float*)d_in[9];
    float* out = (float*)d_out;

    float* ws    = (float*)d_ws;
    float* featT = ws;                               // 256 * B floats
    float* WhT   = ws + (size_t)256 * BT;            // N*192*64
    float* WiT   = WhT + (size_t)NA * G3 * HH;       // N*192*8

    wtrans_kernel<<<NA * G3, 64, 0, stream>>>(Wi, Wh, WiT, WhT);
    gru_kernel<<<dim3(BT / 256, NA), 256, 0, stream>>>(x, WiT, WhT, bh, featT);
    mlp_kernel<<<BT / 32, 256, 0, stream>>>(featT, W0, b0, W1, b1, Wout, bout, out);
}

// Round 3
// 1475.392 us; speedup vs baseline: 2.2116x; 2.1778x over previous
//
#include <hip/hip_runtime.h>
#include <math.h>

#define BT 32768
#define TT 20
#define NA 4
#define DD 8
#define HH 64
#define G3 192   // 3*H
#define MB 64    // batches per GRU block
#define NTH 512  // GRU block threads (8 waves)
#define HPAD 68  // hb row stride: 272B = 16B-aligned, write banks ~2x min

__device__ __forceinline__ float fsig(float x) { return 1.0f / (1.0f + __expf(-x)); }
__device__ __forceinline__ float ftanh(float x) {
    // tanh via exp(-2|x|): e in (0,1], no overflow, no inf/inf NaN
    float e = __expf(-2.0f * fabsf(x));
    float t = (1.0f - e) / (1.0f + e);
    return copysignf(t, x);
}

// GRU, "GEMM view": lane j = hidden index, wave w owns 8 batch columns.
// h in LDS (broadcast reads), weights staged in LDS once per block,
// h_old for the blend kept in registers (same lane computed it last step).
__global__ __launch_bounds__(NTH, 4)
void gru_kernel(const float* __restrict__ x, const float* __restrict__ Wi,
                const float* __restrict__ Wh, const float* __restrict__ bh,
                float* __restrict__ feat) {
    __shared__ float whl[3 * 64 * 64];  // [g][k][j]  48KB
    __shared__ float wil[3 * 8 * 64];   // [g][d][j]   6KB
    __shared__ float hb[64 * HPAD];     // [k][m]    17.4KB
    __shared__ float xb[8 * HPAD];      // [d][m]     2.2KB

    const int tid = threadIdx.x;
    const int j   = tid & 63;
    const int w   = tid >> 6;   // wave 0..7
    const int mb  = w * 8;      // this wave's batch sub-base
    const int n   = blockIdx.y;
    const int bg  = blockIdx.x * MB;

    // ---- stage Wh[n]: src [k][g*64+j] -> whl[g][k][j] (float4 over j) ----
    const float* __restrict__ whg = Wh + (size_t)n * HH * G3;
#pragma unroll
    for (int it = 0; it < 6; ++it) {
        const int s4 = (it * NTH + tid) * 4;           // 6*512*4 = 12288 exactly
        const float4 v = *(const float4*)(whg + s4);
        const int k = s4 / G3;
        const int r = s4 - k * G3;
        const int g = r >> 6, jj = r & 63;
        *(float4*)&whl[(g * 64 + k) * 64 + jj] = v;
    }
    {   // Wi[n]: src [d][g*64+j] -> wil[g][d][j]; 1536 floats = 384 float4
        const int s4 = tid * 4;
        if (s4 < 3 * DD * 64) {
            const float4 v = *(const float4*)(Wi + (size_t)n * DD * G3 + s4);
            const int d = s4 / G3;
            const int r = s4 - d * G3;
            const int g = r >> 6, jj = r & 63;
            *(float4*)&wil[(g * 8 + d) * 64 + jj] = v;
        }
    }
    for (int i = tid; i < 64 * HPAD / 4; i += NTH)     // zero h(0)
        *(float4*)&hb[i * 4] = make_float4(0.f, 0.f, 0.f, 0.f);

    const float bhr = bh[n * G3 + j];
    const float bhz = bh[n * G3 + 64 + j];
    const float bhn = bh[n * G3 + 128 + j];

    const int m0 = tid >> 3, d0 = tid & 7;             // x-staging role
    const float* __restrict__ xrow =
        x + (size_t)(bg + m0) * (TT * NA * DD) + n * DD + d0;

    float hnew[8];
#pragma unroll
    for (int i = 0; i < 8; ++i) hnew[i] = 0.f;

    for (int t = 0; t < TT; ++t) {
        xb[d0 * HPAD + m0] = xrow[t * (NA * DD)];
        __syncthreads();   // barrier A: xb(t) staged, hb(t-1) writes visible

        float ar[8], az[8], an[8], ai[8];
#pragma unroll
        for (int i = 0; i < 8; ++i) { ar[i] = 0.f; az[i] = 0.f; an[i] = 0.f; ai[i] = 0.f; }

        // hidden dots: acc_g[m] += Wh[k][g*64+j] * h[k][m]
#pragma unroll 4
        for (int k = 0; k < 64; ++k) {
            const float wr = whl[k * 64 + j];
            const float wz = whl[(64 + k) * 64 + j];
            const float wn = whl[(128 + k) * 64 + j];
            const float4 h0 = *(const float4*)&hb[k * HPAD + mb];
            const float4 h1 = *(const float4*)&hb[k * HPAD + mb + 4];
            const float hv[8] = {h0.x, h0.y, h0.z, h0.w, h1.x, h1.y, h1.z, h1.w};
#pragma unroll
            for (int i = 0; i < 8; ++i) {
                ar[i] = fmaf(wr, hv[i], ar[i]);
                az[i] = fmaf(wz, hv[i], az[i]);
                an[i] = fmaf(wn, hv[i], an[i]);
            }
        }
        // input dots: r,z fold into same accs; n-gate input kept separate (ai)
#pragma unroll
        for (int d = 0; d < DD; ++d) {
            const float wr = wil[d * 64 + j];
            const float wz = wil[(8 + d) * 64 + j];
            const float wn = wil[(16 + d) * 64 + j];
            const float4 x0 = *(const float4*)&xb[d * HPAD + mb];
            const float4 x1 = *(const float4*)&xb[d * HPAD + mb + 4];
            const float xv[8] = {x0.x, x0.y, x0.z, x0.w, x1.x, x1.y, x1.z, x1.w};
#pragma unroll
            for (int i = 0; i < 8; ++i) {
                ar[i] = fmaf(wr, xv[i], ar[i]);
                az[i] = fmaf(wz, xv[i], az[i]);
                ai[i] = fmaf(wn, xv[i], ai[i]);
            }
        }
        // epilogue: h_old comes from this lane's own hnew[] of last step
#pragma unroll
        for (int i = 0; i < 8; ++i) {
            const float rg = fsig(ar[i] + bhr);
            const float zg = fsig(az[i] + bhz);
            const float ng = ftanh(ai[i] + rg * (an[i] + bhn));
            hnew[i] = fmaf(zg, hnew[i] - ng, ng);   // (1-z)n + z*h_old
        }
        __syncthreads();   // barrier B: all hb/xb reads of step t complete
        *(float4*)&hb[j * HPAD + mb]     = make_float4(hnew[0], hnew[1], hnew[2], hnew[3]);
        *(float4*)&hb[j * HPAD + mb + 4] = make_float4(hnew[4], hnew[5], hnew[6], hnew[7]);
    }

    // feat[b][n*64+j], coalesced across lanes
#pragma unroll
    for (int i = 0; i < 8; ++i)
        feat[(size_t)(bg + mb + i) * 256 + n * 64 + j] = hnew[i];
}

// Fused MLP on feat[B][256]; LDS padded [256][33] -> conflict-free everywhere.
__global__ __launch_bounds__(256, 4)
void mlp_kernel(const float* __restrict__ feat, const float* __restrict__ W0,
                const float* __restrict__ b0, const float* __restrict__ W1,
                const float* __restrict__ b1, const float* __restrict__ Wout,
                const float* __restrict__ bout, float* __restrict__ out) {
    __shared__ float sf[256 * 33];   // [feature][batch], 33.8KB
    const int tid = threadIdx.x;
    const int bl  = tid & 31;
    const int q   = tid >> 5;        // 0..7
    const int bg  = blockIdx.x * 32;

    // stage feat tile: per it, 256 threads read one full batch row (coalesced),
    // write sf[tid*33+it] -> banks (tid+it)%32, conflict-free
#pragma unroll 4
    for (int it = 0; it < 32; ++it)
        sf[tid * 33 + it] = feat[(size_t)(bg + it) * 256 + tid];
    __syncthreads();

    // stage 1: h1[bl][q*32 .. q*32+31]
    float acc[32];
#pragma unroll
    for (int i = 0; i < 32; ++i) acc[i] = b0[q * 32 + i];
#pragma unroll 2
    for (int k = 0; k < 256; ++k) {
        const float f = sf[k * 33 + bl];
        const float4* __restrict__ wv4 = (const float4*)(W0 + (size_t)k * 256 + q * 32);
#pragma unroll
        for (int i = 0; i < 8; ++i) {
            const float4 wv = wv4[i];
            acc[4*i+0] = fmaf(f, wv.x, acc[4*i+0]);
            acc[4*i+1] = fmaf(f, wv.y, acc[4*i+1]);
            acc[4*i+2] = fmaf(f, wv.z, acc[4*i+2]);
            acc[4*i+3] = fmaf(f, wv.w, acc[4*i+3]);
        }
    }
    __syncthreads();   // stage-1 reads done before overwrite
#pragma unroll
    for (int i = 0; i < 32; ++i) {
        const float v = acc[i];
        sf[(q * 32 + i) * 33 + bl] = v > 0.f ? v : 0.f;
    }
    __syncthreads();

    // stage 2: h2[bl][q*16 .. q*16+15]
    float a2[16];
#pragma unroll
    for (int i = 0; i < 16; ++i) a2[i] = b1[q * 16 + i];
#pragma unroll 2
    for (int k = 0; k < 256; ++k) {
        const float f = sf[k * 33 + bl];
        const float4* __restrict__ wv4 = (const float4*)(W1 + (size_t)k * 128 + q * 16);
#pragma unroll
        for (int i = 0; i < 4; ++i) {
            const float4 wv = wv4[i];
            a2[4*i+0] = fmaf(f, wv.x, a2[4*i+0]);
            a2[4*i+1] = fmaf(f, wv.y, a2[4*i+1]);
            a2[4*i+2] = fmaf(f, wv.z, a2[4*i+2]);
            a2[4*i+3] = fmaf(f, wv.w, a2[4*i+3]);
        }
    }
    __syncthreads();
#pragma unroll
    for (int i = 0; i < 16; ++i) {
        const float v = a2[i];
        sf[(q * 16 + i) * 33 + bl] = v > 0.f ? v : 0.f;
    }
    __syncthreads();

    // stage 3: one output per thread (out dim 8 == #q groups)
    float o = bout[q];
#pragma unroll 4
    for (int k = 0; k < 128; ++k)
        o = fmaf(sf[k * 33 + bl], Wout[k * 8 + q], o);
    out[(size_t)(bg + bl) * 8 + q] = o;
}

extern "C" void kernel_launch(void* const* d_in, const int* in_sizes, int n_in,
                              void* d_out, int out_size, void* d_ws, size_t ws_size,
                              hipStream_t stream) {
    const float* x    = (const float*)d_in[0];
    const float* Wi   = (const float*)d_in[1];
    const float* Wh   = (const float*)d_in[2];
    const float* bh   = (const float*)d_in[3];
    const float* W0   = (const float*)d_in[4];
    const float* b0   = (const float*)d_in[5];
    const float* W1   = (const float*)d_in[6];
    const float* b1   = (const float*)d_in[7];
    const float* Wout = (const float*)d_in[8];
    const float* bout = (const float*)d_in[9];
    float* out = (float*)d_out;

    float* feat = (float*)d_ws;   // B * 256 floats

    gru_kernel<<<dim3(BT / MB, NA), NTH, 0, stream>>>(x, Wi, Wh, bh, feat);
    mlp_kernel<<<BT / 32, 256, 0, stream>>>(feat, W0, b0, W1, b1, Wout, bout, out);
}

// Round 4
// 380.800 us; speedup vs baseline: 8.5689x; 3.8744x over previous
//
#include <hip/hip_runtime.h>
#include <math.h>

#define BT 32768
#define TT 20
#define NA 4
#define DD 8
#define HH 64

typedef short short8 __attribute__((ext_vector_type(8)));
typedef float f32x4 __attribute__((ext_vector_type(4)));
typedef unsigned short ushort;
typedef unsigned int uint;

#define SC1 -1.4426950408889634f   // -log2(e)   (r,z gates)
#define SC2 -2.8853900817779268f   // -2log2(e)  (n-hidden+bias, inn)

// ---- bf16 hi/lo split (truncation; lo = exact residual, then truncated) ----
__device__ __forceinline__ void bsplit(float v, ushort& h, ushort& l) {
    uint u = __float_as_uint(v);
    uint hu = u & 0xFFFF0000u;
    h = (ushort)(hu >> 16);
    float r = v - __uint_as_float(hu);
    l = (ushort)(__float_as_uint(r) >> 16);
}

// ================= prep: GRU A-fragments (lane-major, pre-scaled) ==========
// A_ext per gate g: rows j (64, tiled by jt), cols k: [0,64)=Wh, [64,72)=Wi
// (g<2 only), k==72 = bias (g<3), else 0. g==3 = inn (Wi of n-gate only).
// frag id: g<3: (g*3+kq)*2+s ; g==3 (kq==2): 18+s. 20 frags.
// Storage: AG[((n*4+jt)*20 + fid)*64 + lane] = uint4 (8 bf16, k-ascending).
__global__ void prep_gruA(const float* __restrict__ Wh, const float* __restrict__ Wi,
                          const float* __restrict__ bh, uint4* __restrict__ AG) {
    int gid = blockIdx.x * 256 + threadIdx.x;           // 20480 total
    int l = gid & 63;
    int r2 = gid >> 6;                                  // 0..319
    int fid = r2 % 20;
    int jt = (r2 / 20) & 3;
    int n = r2 / 80;
    int s = fid & 1;
    int gk = fid >> 1;
    int g, kq;
    if (gk < 9) { g = gk / 3; kq = gk % 3; } else { g = 3; kq = 2; }
    int j = jt * 16 + (l & 15);
    int lk = (l >> 4) & 3;
    float scale = (g < 2) ? SC1 : SC2;

    uint wds[4];
    for (int i = 0; i < 4; ++i) {
        uint pk = 0;
        for (int half = 0; half < 2; ++half) {
            int e = 2 * i + half;
            int k = kq * 32 + 8 * lk + e;
            float v = 0.f;
            if (g < 3) {
                if (k < 64)            v = Wh[(size_t)(n * 64 + k) * 192 + g * 64 + j];
                else if (k < 72) { if (g < 2) v = Wi[(size_t)(n * 8 + (k - 64)) * 192 + g * 64 + j]; }
                else if (k == 72)      v = bh[n * 192 + g * 64 + j];
            } else {
                if (k >= 64 && k < 72) v = Wi[(size_t)(n * 8 + (k - 64)) * 192 + 128 + j];
            }
            v *= scale;
            ushort hi, lo; bsplit(v, hi, lo);
            ushort b = s ? lo : hi;
            pk |= ((uint)b) << (16 * half);
        }
        wds[i] = pk;
    }
    uint4 u; u.x = wds[0]; u.y = wds[1]; u.z = wds[2]; u.w = wds[3];
    AG[gid] = u;
}

// ================= prep: MLP weight fragments (lane-major) =================
// B-frag for W[k][o]: lane l gets k = kq*32+8*(l>>4)+e, o = nt*16+(l&15).
// dst[gid] with gid = ((nt*NKQ+kq)*2+s)*64+l. Zero-pad cols >= Nreal.
__global__ void prep_mlpW(const float* __restrict__ W, uint4* __restrict__ dst,
                          int NT, int NKQ, int Nreal) {
    int gid = blockIdx.x * 256 + threadIdx.x;
    if (gid >= NT * NKQ * 2 * 64) return;
    int l = gid & 63;
    int s = (gid >> 6) & 1;
    int rr = gid >> 7;
    int kq = rr % NKQ;
    int nt = rr / NKQ;
    int o = nt * 16 + (l & 15);
    int lk = (l >> 4) & 3;
    uint wds[4];
    for (int i = 0; i < 4; ++i) {
        uint pk = 0;
        for (int half = 0; half < 2; ++half) {
            int e = 2 * i + half;
            int k = kq * 32 + 8 * lk + e;
            float v = (o < Nreal) ? W[(size_t)k * Nreal + o] : 0.f;
            ushort hi, lo; bsplit(v, hi, lo);
            ushort b = s ? lo : hi;
            pk |= ((uint)b) << (16 * half);
        }
        wds[i] = pk;
    }
    uint4 u; u.x = wds[0]; u.y = wds[1]; u.z = wds[2]; u.w = wds[3];
    dst[gid] = u;
}

// ============================ GRU (MFMA) ===================================
// Block: 32 batches x 1 agent, 4 waves. Wave w = M-tile jt=w (16 gate-rows
// per gate). Tasks nt in {0,1} = 16-batch column tiles. K_ext = 96:
// [h(64) | x(8) | 1.0 bias row(k=72) | 0]. B in LDS [m][k] k-contig, hi/lo
// planes, double-buffered; one barrier per timestep.
#define LDK 88
#define PLANE (32 * LDK + 32)   // + tail pad (zeroed; spill-reads hit zeros)

__global__ __launch_bounds__(256, 3)
void gru_kernel(const float* __restrict__ x, const uint4* __restrict__ AG,
                ushort* __restrict__ featH, ushort* __restrict__ featL) {
    __shared__ __align__(16) ushort Bs[2][2][PLANE];
    const int tid = threadIdx.x;
    const int l = tid & 63;
    const int w = tid >> 6;        // = jt
    const int lrow = l & 15;
    const int lk = l >> 4;
    const int n = blockIdx.y;
    const int bg = blockIdx.x * 32;

    // zero all LDS (h(0)=0, zero-pad regions, spill pads)
    {
        uint4 z = {0, 0, 0, 0};
        uint4* p = (uint4*)&Bs[0][0][0];
        for (int i = tid; i < (int)(sizeof(Bs) / 16); i += 256) p[i] = z;
    }
    __syncthreads();

    // A-fragments: 20 x (global dwordx4), held in VGPRs for all 20 steps
    short8 A[20];
    const uint4* ab = AG + (size_t)(n * 4 + w) * 1280 + l;
#pragma unroll
    for (int f = 0; f < 20; ++f) {
        uint4 v = ab[f * 64];
        A[f] = *(short8*)&v;
    }

    // x staging role: one (m,d) element per thread per step
    const int m0 = tid >> 3, d0 = tid & 7;
    const float* __restrict__ xp = x + (size_t)(bg + m0) * 640 + n * 8 + d0;

    // stage x(0) + bias rows into buffer 0 (bias row in BOTH buffers)
    {
        float v = xp[0];
        ushort hi, lo; bsplit(v, hi, lo);
        Bs[0][0][m0 * LDK + 64 + d0] = hi;
        Bs[0][1][m0 * LDK + 64 + d0] = lo;
    }
    if (tid < 64) {
        int m = tid & 31, bu = tid >> 5;
        Bs[bu][0][m * LDK + 72] = 0x3F80;  // bf16(1.0); lo plane stays 0
    }
    __syncthreads();

    f32x4 hold[2];
#pragma unroll
    for (int nt = 0; nt < 2; ++nt)
#pragma unroll
        for (int r = 0; r < 4; ++r) hold[nt][r] = 0.f;

    for (int t = 0; t < TT; ++t) {
        const int p = t & 1;
        float xnext = (t < 19) ? xp[(t + 1) * 32] : 0.f;

        const ushort* __restrict__ BH = &Bs[p][0][0];
        const ushort* __restrict__ BL = &Bs[p][1][0];
        ushort* __restrict__ WH = &Bs[p ^ 1][0][0];
        ushort* __restrict__ WL = &Bs[p ^ 1][1][0];

        f32x4 acc[2][4];
#pragma unroll
        for (int nt = 0; nt < 2; ++nt)
#pragma unroll
            for (int g = 0; g < 4; ++g)
#pragma unroll
                for (int r = 0; r < 4; ++r) acc[nt][g][r] = 0.f;

#pragma unroll
        for (int nt = 0; nt < 2; ++nt) {
#pragma unroll
            for (int kq = 0; kq < 3; ++kq) {
                const int boff = (nt * 16 + lrow) * LDK + kq * 32 + 8 * lk;
                short8 bhf = *(const short8*)&BH[boff];
                short8 blf = *(const short8*)&BL[boff];
#pragma unroll
                for (int g = 0; g < 3; ++g) {
                    acc[nt][g] = __builtin_amdgcn_mfma_f32_16x16x32_bf16(A[(g * 3 + kq) * 2 + 0], bhf, acc[nt][g], 0, 0, 0);
                    acc[nt][g] = __builtin_amdgcn_mfma_f32_16x16x32_bf16(A[(g * 3 + kq) * 2 + 1], bhf, acc[nt][g], 0, 0, 0);
                    acc[nt][g] = __builtin_amdgcn_mfma_f32_16x16x32_bf16(A[(g * 3 + kq) * 2 + 0], blf, acc[nt][g], 0, 0, 0);
                }
                if (kq == 2) {
                    acc[nt][3] = __builtin_amdgcn_mfma_f32_16x16x32_bf16(A[18], bhf, acc[nt][3], 0, 0, 0);
                    acc[nt][3] = __builtin_amdgcn_mfma_f32_16x16x32_bf16(A[19], bhf, acc[nt][3], 0, 0, 0);
                    acc[nt][3] = __builtin_amdgcn_mfma_f32_16x16x32_bf16(A[18], blf, acc[nt][3], 0, 0, 0);
                }
            }
        }

        // epilogue: acc pre-scaled -> sigmoid/tanh are rcp(1+exp2(.))
#pragma unroll
        for (int nt = 0; nt < 2; ++nt) {
            ushort hh[4], hl[4];
#pragma unroll
            for (int r = 0; r < 4; ++r) {
                float rg = __builtin_amdgcn_rcpf(1.f + __builtin_amdgcn_exp2f(acc[nt][0][r]));
                float zg = __builtin_amdgcn_rcpf(1.f + __builtin_amdgcn_exp2f(acc[nt][1][r]));
                float sarg = fmaf(rg, acc[nt][2][r], acc[nt][3][r]);
                float sg = __builtin_amdgcn_rcpf(1.f + __builtin_amdgcn_exp2f(sarg));
                float ng = fmaf(2.f, sg, -1.f);                 // tanh
                float hv = fmaf(zg, hold[nt][r] - ng, ng);      // (1-z)n + z h
                hold[nt][r] = hv;
                bsplit(hv, hh[r], hl[r]);
            }
            const int wboff = (nt * 16 + lrow) * LDK + w * 16 + 4 * lk;
            uint2 ph, pl;
            ph.x = (uint)hh[0] | ((uint)hh[1] << 16);
            ph.y = (uint)hh[2] | ((uint)hh[3] << 16);
            pl.x = (uint)hl[0] | ((uint)hl[1] << 16);
            pl.y = (uint)hl[2] | ((uint)hl[3] << 16);
            *(uint2*)&WH[wboff] = ph;
            *(uint2*)&WL[wboff] = pl;
        }
        if (t < 19) {
            ushort hi, lo; bsplit(xnext, hi, lo);
            WH[m0 * LDK + 64 + d0] = hi;
            WL[m0 * LDK + 64 + d0] = lo;
        }
        __syncthreads();
    }

    // write feat as split bf16 planes (MFMA-A-ready for the MLP)
#pragma unroll
    for (int nt = 0; nt < 2; ++nt) {
        ushort fh[4], fl[4];
#pragma unroll
        for (int r = 0; r < 4; ++r) bsplit(hold[nt][r], fh[r], fl[r]);
        uint2 ph, pl;
        ph.x = (uint)fh[0] | ((uint)fh[1] << 16);
        ph.y = (uint)fh[2] | ((uint)fh[3] << 16);
        pl.x = (uint)fl[0] | ((uint)fl[1] << 16);
        pl.y = (uint)fl[2] | ((uint)fl[3] << 16);
        size_t fo = (size_t)(bg + nt * 16 + lrow) * 256 + n * 64 + w * 16 + 4 * lk;
        *(uint2*)&featH[fo] = ph;
        *(uint2*)&featL[fo] = pl;
    }
}

// ============================ MLP (MFMA) ===================================
// Block: 32 batch rows, 4 waves. L0: wave w -> nt = w*4+q (out-cols), bt 0/1.
// h1/h2 staged split-bf16 in LDS [b][k] (k-contig). W frags from prepped
// global (L2-hot). Final layer on waves 0-1 (N=8 padded to 16 with zeros).
__global__ __launch_bounds__(256, 3)
void mlp_kernel(const ushort* __restrict__ featH, const ushort* __restrict__ featL,
                const uint4* __restrict__ W0F, const uint4* __restrict__ W1F,
                const uint4* __restrict__ W2F, const float* __restrict__ b0,
                const float* __restrict__ b1, const float* __restrict__ bout,
                float* __restrict__ out) {
    __shared__ __align__(16) ushort s1[2][32][264];
    __shared__ __align__(16) ushort s2[2][32][136];
    const int tid = threadIdx.x;
    const int l = tid & 63;
    const int w = tid >> 6;
    const int lrow = l & 15;
    const int lk = l >> 4;
    const int bg = blockIdx.x * 32;

    // ---- L0: feat[32,256] @ W0[256,256] ----
    f32x4 a0[2][4];
#pragma unroll
    for (int bt = 0; bt < 2; ++bt)
#pragma unroll
        for (int q = 0; q < 4; ++q)
#pragma unroll
            for (int r = 0; r < 4; ++r) a0[bt][q][r] = 0.f;

    for (int kq = 0; kq < 8; ++kq) {
        short8 aH[2], aL[2];
#pragma unroll
        for (int bt = 0; bt < 2; ++bt) {
            size_t off = (size_t)(bg + bt * 16 + lrow) * 256 + kq * 32 + 8 * lk;
            aH[bt] = *(const short8*)&featH[off];
            aL[bt] = *(const short8*)&featL[off];
        }
#pragma unroll
        for (int q = 0; q < 4; ++q) {
            int nt = w * 4 + q;
            short8 bH = *(const short8*)&W0F[((nt * 8 + kq) * 2 + 0) * 64 + l];
            short8 bL = *(const short8*)&W0F[((nt * 8 + kq) * 2 + 1) * 64 + l];
#pragma unroll
            for (int bt = 0; bt < 2; ++bt) {
                a0[bt][q] = __builtin_amdgcn_mfma_f32_16x16x32_bf16(aH[bt], bH, a0[bt][q], 0, 0, 0);
                a0[bt][q] = __builtin_amdgcn_mfma_f32_16x16x32_bf16(aL[bt], bH, a0[bt][q], 0, 0, 0);
                a0[bt][q] = __builtin_amdgcn_mfma_f32_16x16x32_bf16(aH[bt], bL, a0[bt][q], 0, 0, 0);
            }
        }
    }
#pragma unroll
    for (int bt = 0; bt < 2; ++bt)
#pragma unroll
        for (int q = 0; q < 4; ++q) {
            int nn = (w * 4 + q) * 16 + lrow;
            float bias = b0[nn];
            int row0 = bt * 16 + 4 * lk;
#pragma unroll
            for (int r = 0; r < 4; ++r) {
                float v = a0[bt][q][r] + bias;
                v = v > 0.f ? v : 0.f;
                ushort hi, lo; bsplit(v, hi, lo);
                s1[0][row0 + r][nn] = hi;
                s1[1][row0 + r][nn] = lo;
            }
        }
    __syncthreads();

    // ---- L1: h1[32,256] @ W1[256,128] ----
    f32x4 a1[2][2];
#pragma unroll
    for (int bt = 0; bt < 2; ++bt)
#pragma unroll
        for (int u = 0; u < 2; ++u)
#pragma unroll
            for (int r = 0; r < 4; ++r) a1[bt][u][r] = 0.f;

    for (int kq = 0; kq < 8; ++kq) {
        short8 aH[2], aL[2];
#pragma unroll
        for (int bt = 0; bt < 2; ++bt) {
            aH[bt] = *(const short8*)&s1[0][bt * 16 + lrow][kq * 32 + 8 * lk];
            aL[bt] = *(const short8*)&s1[1][bt * 16 + lrow][kq * 32 + 8 * lk];
        }
#pragma unroll
        for (int u = 0; u < 2; ++u) {
            int nt1 = w + 4 * u;
            short8 bH = *(const short8*)&W1F[((nt1 * 8 + kq) * 2 + 0) * 64 + l];
            short8 bL = *(const short8*)&W1F[((nt1 * 8 + kq) * 2 + 1) * 64 + l];
#pragma unroll
            for (int bt = 0; bt < 2; ++bt) {
                a1[bt][u] = __builtin_amdgcn_mfma_f32_16x16x32_bf16(aH[bt], bH, a1[bt][u], 0, 0, 0);
                a1[bt][u] = __builtin_amdgcn_mfma_f32_16x16x32_bf16(aL[bt], bH, a1[bt][u], 0, 0, 0);
                a1[bt][u] = __builtin_amdgcn_mfma_f32_16x16x32_bf16(aH[bt], bL, a1[bt][u], 0, 0, 0);
            }
        }
    }
#pragma unroll
    for (int bt = 0; bt < 2; ++bt)
#pragma unroll
        for (int u = 0; u < 2; ++u) {
            int nn = (w + 4 * u) * 16 + lrow;
            float bias = b1[nn];
            int row0 = bt * 16 + 4 * lk;
#pragma unroll
            for (int r = 0; r < 4; ++r) {
                float v = a1[bt][u][r] + bias;
                v = v > 0.f ? v : 0.f;
                ushort hi, lo; bsplit(v, hi, lo);
                s2[0][row0 + r][nn] = hi;
                s2[1][row0 + r][nn] = lo;
            }
        }
    __syncthreads();

    // ---- L2: h2[32,128] @ Wout[128,8] (cols padded to 16) ----
    if (w < 2) {
        const int bt = w;
        f32x4 a2;
#pragma unroll
        for (int r = 0; r < 4; ++r) a2[r] = 0.f;
        for (int kq = 0; kq < 4; ++kq) {
            short8 aH = *(const short8*)&s2[0][bt * 16 + lrow][kq * 32 + 8 * lk];
            short8 aL = *(const short8*)&s2[1][bt * 16 + lrow][kq * 32 + 8 * lk];
            short8 bH = *(const short8*)&W2F[(kq * 2 + 0) * 64 + l];
            short8 bL = *(const short8*)&W2F[(kq * 2 + 1) * 64 + l];
            a2 = __builtin_amdgcn_mfma_f32_16x16x32_bf16(aH, bH, a2, 0, 0, 0);
            a2 = __builtin_amdgcn_mfma_f32_16x16x32_bf16(aL, bH, a2, 0, 0, 0);
            a2 = __builtin_amdgcn_mfma_f32_16x16x32_bf16(aH, bL, a2, 0, 0, 0);
        }
        if (lrow < 8) {
            float bo = bout[lrow];
#pragma unroll
            for (int r = 0; r < 4; ++r)
                out[(size_t)(bg + bt * 16 + 4 * lk + r) * 8 + lrow] = a2[r] + bo;
        }
    }
}

extern "C" void kernel_launch(void* const* d_in, const int* in_sizes, int n_in,
                              void* d_out, int out_size, void* d_ws, size_t ws_size,
                              hipStream_t stream) {
    const float* x    = (const float*)d_in[0];
    const float* Wi   = (const float*)d_in[1];
    const float* Wh   = (const float*)d_in[2];
    const float* bh   = (const float*)d_in[3];
    const float* W0   = (const float*)d_in[4];
    const float* b0   = (const float*)d_in[5];
    const float* W1   = (const float*)d_in[6];
    const float* b1   = (const float*)d_in[7];
    const float* Wout = (const float*)d_in[8];
    const float* bout = (const float*)d_in[9];

    char* wsb = (char*)d_ws;
    ushort* featH = (ushort*)wsb;                                  // B*256 bf16
    ushort* featL = (ushort*)(wsb + 16777216);
    uint4* AG  = (uint4*)(wsb + 33554432);                         // 327680 B
    uint4* W0F = (uint4*)(wsb + 33554432 + 327680);                // 262144 B
    uint4* W1F = (uint4*)(wsb + 33554432 + 327680 + 262144);       // 131072 B
    uint4* W2F = (uint4*)(wsb + 33554432 + 327680 + 262144 + 131072); // 8192 B

    prep_gruA<<<80, 256, 0, stream>>>(Wh, Wi, bh, AG);
    prep_mlpW<<<64, 256, 0, stream>>>(W0, W0F, 16, 8, 256);
    prep_mlpW<<<32, 256, 0, stream>>>(W1, W1F, 8, 8, 128);
    prep_mlpW<<<2, 256, 0, stream>>>(Wout, W2F, 1, 4, 8);
    gru_kernel<<<dim3(BT / 32, NA), 256, 0, stream>>>(x, AG, featH, featL);
    mlp_kernel<<<BT / 32, 256, 0, stream>>>(featH, featL, W0F, W1F, W2F, b0, b1, bout, (float*)d_out);
}

// Round 5
// 378.611 us; speedup vs baseline: 8.6185x; 1.0058x over previous
//
#include <hip/hip_runtime.h>
#include <math.h>

#define BT 32768
#define TT 20
#define NA 4
#define DD 8
#define HH 64

typedef _Float16 half8 __attribute__((ext_vector_type(8)));
typedef float f32x4 __attribute__((ext_vector_type(4)));
typedef unsigned short ushort;
typedef unsigned int uint;

#define SC1 -1.4426950408889634f   // -log2(e)   (r,z gates)
#define SC2 -2.8853900817779268f   // -2log2(e)  (n-hidden+bias, inn)

__device__ __forceinline__ ushort f16b(float v) {
    _Float16 h = (_Float16)v;           // RTN
    return *(ushort*)&h;
}
__device__ __forceinline__ void fsplit(float v, ushort& hi, ushort& lo) {
    _Float16 h = (_Float16)v;           // RTN
    hi = *(ushort*)&h;
    float r = v - (float)h;             // exact residual
    _Float16 lw = (_Float16)r;
    lo = *(ushort*)&lw;
}

// ============ merged prep: GRU A-frags (x3, scaled) + MLP W-frags (x2) ======
// gruA ids [0,20480): AG[((n*4+jt)*20+fid)*64+l], fid=(g*3+kq)*2+s (g<3) / 18+s (inn)
// W0F ids [20480,28672): [(nt*8+kq)*64+l] single fp16; W1F [28672,32768); W2F [32768,33024)
__global__ void prep_all(const float* __restrict__ Wh, const float* __restrict__ Wi,
                         const float* __restrict__ bh, const float* __restrict__ W0,
                         const float* __restrict__ W1, const float* __restrict__ Wout,
                         uint4* __restrict__ AG, uint4* __restrict__ W0F,
                         uint4* __restrict__ W1F, uint4* __restrict__ W2F) {
    const int gid = blockIdx.x * 256 + threadIdx.x;
    if (gid < 20480) {
        const int l = gid & 63;
        const int r2 = gid >> 6;
        const int fid = r2 % 20;
        const int jt = (r2 / 20) & 3;
        const int n = r2 / 80;
        const int s = fid & 1;
        const int gk = fid >> 1;
        int g, kq;
        if (gk < 9) { g = gk / 3; kq = gk % 3; } else { g = 3; kq = 2; }
        const int j = jt * 16 + (l & 15);
        const int lk = (l >> 4) & 3;
        const float scale = (g < 2) ? SC1 : SC2;
        uint wds[4];
        for (int i = 0; i < 4; ++i) {
            uint pk = 0;
            for (int hf = 0; hf < 2; ++hf) {
                const int e = 2 * i + hf;
                const int k = kq * 32 + 8 * lk + e;
                float v = 0.f;
                if (g < 3) {
                    if (k < 64)       v = Wh[(size_t)(n * 64 + k) * 192 + g * 64 + j];
                    else if (k < 72)  { if (g < 2) v = Wi[(size_t)(n * 8 + (k - 64)) * 192 + g * 64 + j]; }
                    else if (k == 72) v = bh[n * 192 + g * 64 + j];
                } else {
                    if (k >= 64 && k < 72) v = Wi[(size_t)(n * 8 + (k - 64)) * 192 + 128 + j];
                }
                v *= scale;
                ushort hi, lo; fsplit(v, hi, lo);
                pk |= ((uint)(s ? lo : hi)) << (16 * hf);
            }
            wds[i] = pk;
        }
        uint4 u; u.x = wds[0]; u.y = wds[1]; u.z = wds[2]; u.w = wds[3];
        AG[gid] = u;
    } else if (gid < 33024) {
        int id; const float* W; uint4* dst; int Nreal;
        if (gid < 28672)      { id = gid - 20480; W = W0;   dst = W0F; Nreal = 256; }
        else if (gid < 32768) { id = gid - 28672; W = W1;   dst = W1F; Nreal = 128; }
        else                  { id = gid - 32768; W = Wout; dst = W2F; Nreal = 8;   }
        const int l = id & 63;
        const int rr = id >> 6;
        const int kq = rr & 7;          // for W2F rr=0..3 -> kq=rr, nt=0
        const int nt = rr >> 3;
        const int o = nt * 16 + (l & 15);
        const int lk = (l >> 4) & 3;
        const int ocols = (Nreal < 16) ? Nreal : ((Nreal + 15) & ~15);  // W stride
        uint wds[4];
        for (int i = 0; i < 4; ++i) {
            uint pk = 0;
            for (int hf = 0; hf < 2; ++hf) {
                const int e = 2 * i + hf;
                const int k = kq * 32 + 8 * lk + e;
                float v = 0.f;
                if (o < Nreal) v = W[(size_t)k * Nreal + o];
                pk |= ((uint)f16b(v)) << (16 * hf);
            }
            wds[i] = pk;
        }
        uint4 u; u.x = wds[0]; u.y = wds[1]; u.z = wds[2]; u.w = wds[3];
        dst[id] = u;
        (void)ocols;
    }
}

// ============================ GRU (fp16 MFMA, x3) ==========================
// Block: 32 batches x 1 agent, 4 waves: wave = (jt2 = w>>1 -> j-tiles {2jt2,2jt2+1},
// nt = w&1 -> one 16-batch tile). B in LDS [m][k], 128-ushort rows (256B == 0 mod
// 128B banks) + granule XOR swizzle g^=(row&7) -> conflict-free reads AND writes.
// K_ext = 96: [h(64) | x(8) | bias-1.0(k=72) | 0]. 1 barrier/step, dbuf.
__global__ __launch_bounds__(256, 2)
void gru_kernel(const float* __restrict__ x, const uint4* __restrict__ AG,
                ushort* __restrict__ featH, ushort* __restrict__ featL) {
    __shared__ __align__(16) ushort Bs[2][2][32 * 128];
    const int tid = threadIdx.x;
    const int l = tid & 63;
    const int w = tid >> 6;
    const int lrow = l & 15;
    const int lk = l >> 4;
    const int jt2 = w >> 1;
    const int nt = w & 1;
    const int n = blockIdx.y;
    const int bg = blockIdx.x * 32;

    {   // zero all LDS (h(0)=0, pad granules stay 0)
        uint4 z = {0, 0, 0, 0};
        uint4* p = (uint4*)&Bs[0][0][0];
        for (int i = tid; i < 2048; i += 256) p[i] = z;
    }
    __syncthreads();

    // A-fragments: 40 x uint4, VGPR-resident for all 20 steps
    half8 A[2][20];
#pragma unroll
    for (int jl = 0; jl < 2; ++jl) {
        const uint4* __restrict__ ab = AG + (size_t)((n * 4 + (jt2 * 2 + jl)) * 20) * 64 + l;
#pragma unroll
        for (int f = 0; f < 20; ++f) {
            uint4 v = ab[f * 64];
            A[jl][f] = *(half8*)&v;
        }
    }

    const int m0 = tid >> 3, d0 = tid & 7;
    const float* __restrict__ xp = x + (size_t)(bg + m0) * 640 + n * 8 + d0;

    {   // stage x(0) -> buf0 (granule 8, swizzled)
        float v = xp[0];
        ushort hi, lo; fsplit(v, hi, lo);
        const int gsw = 8 ^ (m0 & 7);
        Bs[0][0][m0 * 128 + gsw * 8 + d0] = hi;
        Bs[0][1][m0 * 128 + gsw * 8 + d0] = lo;
    }
    if (tid < 64) {   // bias row k=72 (granule 9) = 1.0 in BOTH buffers, hi plane
        const int m = tid & 31, bu = tid >> 5;
        Bs[bu][0][m * 128 + (9 ^ (m & 7)) * 8 + 0] = 0x3C00;
    }
    __syncthreads();

    f32x4 hold[2];
#pragma unroll
    for (int jl = 0; jl < 2; ++jl)
#pragma unroll
        for (int r = 0; r < 4; ++r) hold[jl][r] = 0.f;

    const int rbase = (nt * 16 + lrow) * 128;
    const int key = lrow & 7;

    for (int t = 0; t < TT; ++t) {
        const int p = t & 1;
        float xnext = 0.f;
        if (t < TT - 1) xnext = xp[(t + 1) * 32];

        const ushort* __restrict__ BH = &Bs[p][0][0];
        const ushort* __restrict__ BL = &Bs[p][1][0];
        ushort* __restrict__ WH = &Bs[p ^ 1][0][0];
        ushort* __restrict__ WL = &Bs[p ^ 1][1][0];

        f32x4 acc[2][4];
#pragma unroll
        for (int jl = 0; jl < 2; ++jl)
#pragma unroll
            for (int g = 0; g < 4; ++g)
#pragma unroll
                for (int r = 0; r < 4; ++r) acc[jl][g][r] = 0.f;

#pragma unroll
        for (int kq = 0; kq < 3; ++kq) {
            const int gsw = (kq * 4 + lk) ^ key;
            const half8 bhf = *(const half8*)&BH[rbase + gsw * 8];
            const half8 blf = *(const half8*)&BL[rbase + gsw * 8];
#pragma unroll
            for (int jl = 0; jl < 2; ++jl) {
#pragma unroll
                for (int g = 0; g < 3; ++g) {
                    acc[jl][g] = __builtin_amdgcn_mfma_f32_16x16x32_f16(A[jl][(g * 3 + kq) * 2 + 0], bhf, acc[jl][g], 0, 0, 0);
                    acc[jl][g] = __builtin_amdgcn_mfma_f32_16x16x32_f16(A[jl][(g * 3 + kq) * 2 + 1], bhf, acc[jl][g], 0, 0, 0);
                    acc[jl][g] = __builtin_amdgcn_mfma_f32_16x16x32_f16(A[jl][(g * 3 + kq) * 2 + 0], blf, acc[jl][g], 0, 0, 0);
                }
                if (kq == 2) {
                    acc[jl][3] = __builtin_amdgcn_mfma_f32_16x16x32_f16(A[jl][18], bhf, acc[jl][3], 0, 0, 0);
                    acc[jl][3] = __builtin_amdgcn_mfma_f32_16x16x32_f16(A[jl][19], bhf, acc[jl][3], 0, 0, 0);
                    acc[jl][3] = __builtin_amdgcn_mfma_f32_16x16x32_f16(A[jl][18], blf, acc[jl][3], 0, 0, 0);
                }
            }
        }

        // epilogue: acc pre-scaled -> sigmoid/tanh = rcp(1+exp2(.))
#pragma unroll
        for (int jl = 0; jl < 2; ++jl) {
            float hv[4];
#pragma unroll
            for (int r = 0; r < 4; ++r) {
                const float rg = __builtin_amdgcn_rcpf(1.f + __builtin_amdgcn_exp2f(acc[jl][0][r]));
                const float zg = __builtin_amdgcn_rcpf(1.f + __builtin_amdgcn_exp2f(acc[jl][1][r]));
                const float sarg = fmaf(rg, acc[jl][2][r], acc[jl][3][r]);
                const float sg = __builtin_amdgcn_rcpf(1.f + __builtin_amdgcn_exp2f(sarg));
                const float ng = fmaf(2.f, sg, -1.f);
                hv[r] = fmaf(zg, hold[jl][r] - ng, ng);
                hold[jl][r] = hv[r];
            }
            if (t < TT - 1) {
                ushort hh[4], hl[4];
#pragma unroll
                for (int r = 0; r < 4; ++r) fsplit(hv[r], hh[r], hl[r]);
                const int jtg = jt2 * 2 + jl;
                const int gsw = (2 * jtg + (lk >> 1)) ^ key;
                const int off = rbase + gsw * 8 + 4 * (lk & 1);
                uint2 ph, pl;
                ph.x = (uint)hh[0] | ((uint)hh[1] << 16);
                ph.y = (uint)hh[2] | ((uint)hh[3] << 16);
                pl.x = (uint)hl[0] | ((uint)hl[1] << 16);
                pl.y = (uint)hl[2] | ((uint)hl[3] << 16);
                *(uint2*)&WH[off] = ph;
                *(uint2*)&WL[off] = pl;
            }
        }
        if (t < TT - 1) {
            ushort hi, lo; fsplit(xnext, hi, lo);
            const int gsw = 8 ^ (m0 & 7);
            WH[m0 * 128 + gsw * 8 + d0] = hi;
            WL[m0 * 128 + gsw * 8 + d0] = lo;
        }
        __syncthreads();
    }

    // feat as fp16 hi/lo planes [B][256] (MFMA-A-ready for MLP)
#pragma unroll
    for (int jl = 0; jl < 2; ++jl) {
        ushort fh[4], fl[4];
#pragma unroll
        for (int r = 0; r < 4; ++r) fsplit(hold[jl][r], fh[r], fl[r]);
        uint2 ph, pl;
        ph.x = (uint)fh[0] | ((uint)fh[1] << 16);
        ph.y = (uint)fh[2] | ((uint)fh[3] << 16);
        pl.x = (uint)fl[0] | ((uint)fl[1] << 16);
        pl.y = (uint)fl[2] | ((uint)fl[3] << 16);
        const size_t fo = (size_t)(bg + nt * 16 + lrow) * 256 + n * 64 + (jt2 * 2 + jl) * 16 + 4 * lk;
        *(uint2*)&featH[fo] = ph;
        *(uint2*)&featL[fo] = pl;
    }
}

// ============================ MLP (fp16 MFMA, x2: act-split, W single) ======
// Block: 32 batches, 4 waves. L0: A straight from global feat planes, B = W0F
// frags (L2-hot). h1/h2 in LDS, 256B-multiple rows + granule XOR swizzle.
__global__ __launch_bounds__(256, 3)
void mlp_kernel(const ushort* __restrict__ featH, const ushort* __restrict__ featL,
                const uint4* __restrict__ W0F, const uint4* __restrict__ W1F,
                const uint4* __restrict__ W2F, const float* __restrict__ b0,
                const float* __restrict__ b1, const float* __restrict__ bout,
                float* __restrict__ out) {
    __shared__ __align__(16) ushort s1[2][32 * 256];
    __shared__ __align__(16) ushort s2[2][32 * 128];
    const int tid = threadIdx.x;
    const int l = tid & 63;
    const int w = tid >> 6;
    const int lrow = l & 15;
    const int lk = l >> 4;
    const int bg = blockIdx.x * 32;

    // ---- L0: feat[32,256] @ W0[256,256] ----
    f32x4 a0[2][4];
#pragma unroll
    for (int bt = 0; bt < 2; ++bt)
#pragma unroll
        for (int q = 0; q < 4; ++q)
#pragma unroll
            for (int r = 0; r < 4; ++r) a0[bt][q][r] = 0.f;

#pragma unroll 2
    for (int kq = 0; kq < 8; ++kq) {
        half8 aH[2], aL[2];
#pragma unroll
        for (int bt = 0; bt < 2; ++bt) {
            const size_t off = (size_t)(bg + bt * 16 + lrow) * 256 + kq * 32 + 8 * lk;
            aH[bt] = *(const half8*)&featH[off];
            aL[bt] = *(const half8*)&featL[off];
        }
#pragma unroll
        for (int q = 0; q < 4; ++q) {
            const uint4 bv = W0F[((w * 4 + q) * 8 + kq) * 64 + l];
            const half8 bw = *(const half8*)&bv;
#pragma unroll
            for (int bt = 0; bt < 2; ++bt) {
                a0[bt][q] = __builtin_amdgcn_mfma_f32_16x16x32_f16(aH[bt], bw, a0[bt][q], 0, 0, 0);
                a0[bt][q] = __builtin_amdgcn_mfma_f32_16x16x32_f16(aL[bt], bw, a0[bt][q], 0, 0, 0);
            }
        }
    }
#pragma unroll
    for (int bt = 0; bt < 2; ++bt)
#pragma unroll
        for (int q = 0; q < 4; ++q) {
            const int nn = (w * 4 + q) * 16 + lrow;
            const float bias = b0[nn];
            const int gc = nn >> 3, sub = nn & 7;
#pragma unroll
            for (int r = 0; r < 4; ++r) {
                const int row = bt * 16 + 4 * lk + r;
                float v = a0[bt][q][r] + bias;
                v = v > 0.f ? v : 0.f;
                ushort hi, lo; fsplit(v, hi, lo);
                const int gsw = gc ^ (row & 7);
                s1[0][row * 256 + gsw * 8 + sub] = hi;
                s1[1][row * 256 + gsw * 8 + sub] = lo;
            }
        }
    __syncthreads();

    // ---- L1: h1[32,256] @ W1[256,128] ----
    f32x4 a1[2][2];
#pragma unroll
    for (int bt = 0; bt < 2; ++bt)
#pragma unroll
        for (int u = 0; u < 2; ++u)
#pragma unroll
            for (int r = 0; r < 4; ++r) a1[bt][u][r] = 0.f;

#pragma unroll 2
    for (int kq = 0; kq < 8; ++kq) {
        half8 aH[2], aL[2];
#pragma unroll
        for (int bt = 0; bt < 2; ++bt) {
            const int row = bt * 16 + lrow;
            const int gsw = (kq * 4 + lk) ^ (row & 7);
            aH[bt] = *(const half8*)&s1[0][row * 256 + gsw * 8];
            aL[bt] = *(const half8*)&s1[1][row * 256 + gsw * 8];
        }
#pragma unroll
        for (int u = 0; u < 2; ++u) {
            const uint4 bv = W1F[((w + 4 * u) * 8 + kq) * 64 + l];
            const half8 bw = *(const half8*)&bv;
#pragma unroll
            for (int bt = 0; bt < 2; ++bt) {
                a1[bt][u] = __builtin_amdgcn_mfma_f32_16x16x32_f16(aH[bt], bw, a1[bt][u], 0, 0, 0);
                a1[bt][u] = __builtin_amdgcn_mfma_f32_16x16x32_f16(aL[bt], bw, a1[bt][u], 0, 0, 0);
            }
        }
    }
#pragma unroll
    for (int bt = 0; bt < 2; ++bt)
#pragma unroll
        for (int u = 0; u < 2; ++u) {
            const int nn = (w + 4 * u) * 16 + lrow;
            const float bias = b1[nn];
            const int gc = nn >> 3, sub = nn & 7;
#pragma unroll
            for (int r = 0; r < 4; ++r) {
                const int row = bt * 16 + 4 * lk + r;
                float v = a1[bt][u][r] + bias;
                v = v > 0.f ? v : 0.f;
                ushort hi, lo; fsplit(v, hi, lo);
                const int gsw = gc ^ (row & 7);
                s2[0][row * 128 + gsw * 8 + sub] = hi;
                s2[1][row * 128 + gsw * 8 + sub] = lo;
            }
        }
    __syncthreads();

    // ---- L2: h2[32,128] @ Wout[128,8->16pad], waves 0-1 ----
    if (w < 2) {
        const int bt = w;
        f32x4 a2;
#pragma unroll
        for (int r = 0; r < 4; ++r) a2[r] = 0.f;
#pragma unroll
        for (int kq = 0; kq < 4; ++kq) {
            const int row = bt * 16 + lrow;
            const int gsw = (kq * 4 + lk) ^ (row & 7);
            const half8 aH = *(const half8*)&s2[0][row * 128 + gsw * 8];
            const half8 aL = *(const half8*)&s2[1][row * 128 + gsw * 8];
            const uint4 bv = W2F[kq * 64 + l];
            const half8 bw = *(const half8*)&bv;
            a2 = __builtin_amdgcn_mfma_f32_16x16x32_f16(aH, bw, a2, 0, 0, 0);
            a2 = __builtin_amdgcn_mfma_f32_16x16x32_f16(aL, bw, a2, 0, 0, 0);
        }
        if (lrow < 8) {
            const float bo = bout[lrow];
#pragma unroll
            for (int r = 0; r < 4; ++r)
                out[(size_t)(bg + bt * 16 + 4 * lk + r) * 8 + lrow] = a2[r] + bo;
        }
    }
}

extern "C" void kernel_launch(void* const* d_in, const int* in_sizes, int n_in,
                              void* d_out, int out_size, void* d_ws, size_t ws_size,
                              hipStream_t stream) {
    const float* x    = (const float*)d_in[0];
    const float* Wi   = (const float*)d_in[1];
    const float* Wh   = (const float*)d_in[2];
    const float* bh   = (const float*)d_in[3];
    const float* W0   = (const float*)d_in[4];
    const float* b0   = (const float*)d_in[5];
    const float* W1   = (const float*)d_in[6];
    const float* b1   = (const float*)d_in[7];
    const float* Wout = (const float*)d_in[8];
    const float* bout = (const float*)d_in[9];

    char* wsb = (char*)d_ws;
    ushort* featH = (ushort*)wsb;                                   // 16 MB
    ushort* featL = (ushort*)(wsb + 16777216);                      // 16 MB
    uint4* AG  = (uint4*)(wsb + 33554432);                          // 327680 B
    uint4* W0F = (uint4*)(wsb + 33554432 + 327680);                 // 131072 B
    uint4* W1F = (uint4*)(wsb + 33554432 + 327680 + 131072);        // 65536 B
    uint4* W2F = (uint4*)(wsb + 33554432 + 327680 + 131072 + 65536);// 4096 B

    prep_all<<<129, 256, 0, stream>>>(Wh, Wi, bh, W0, W1, Wout, AG, W0F, W1F, W2F);
    gru_kernel<<<dim3(BT / 32, NA), 256, 0, stream>>>(x, AG, featH, featL);
    mlp_kernel<<<BT / 32, 256, 0, stream>>>(featH, featL, W0F, W1F, W2F, b0, b1, bout, (float*)d_out);
}

// Round 6
// 328.323 us; speedup vs baseline: 9.9385x; 1.1532x over previous
//
#include <hip/hip_runtime.h>
#include <math.h>

#define BT 32768
#define TT 20
#define NA 4
#define DD 8
#define HH 64

typedef _Float16 half8 __attribute__((ext_vector_type(8)));
typedef float f32x4 __attribute__((ext_vector_type(4)));
typedef unsigned short ushort;
typedef unsigned int uint;

#define SC1 -1.4426950408889634f   // -log2(e)   (r,z gates)
#define SC2 -2.8853900817779268f   // -2log2(e)  (n-hidden+bias, inn)

__device__ __forceinline__ ushort f16b(float v) {
    _Float16 h = (_Float16)v;           // RTN
    return *(ushort*)&h;
}
__device__ __forceinline__ void fsplit(float v, ushort& hi, ushort& lo) {
    _Float16 h = (_Float16)v;           // RTN
    hi = *(ushort*)&h;
    float r = v - (float)h;             // exact residual
    _Float16 lw = (_Float16)r;
    lo = *(ushort*)&lw;
}

// ============ merged prep: GRU A-frags (hi/lo, scaled) + MLP W-frags ========
// gruA ids [0,20480): AG[((n*4+jt)*20+fid)*64+l], fid=(g*3+kq)*2+s (g<3) / 18+s (inn)
// K layout: kq0,1 = h(64); kq2 = x(8)@64..71 | bias@72 | zeros.
// W0F ids [20480,28672); W1F [28672,32768); W2F [32768,33024) — single fp16.
__global__ void prep_all(const float* __restrict__ Wh, const float* __restrict__ Wi,
                         const float* __restrict__ bh, const float* __restrict__ W0,
                         const float* __restrict__ W1, const float* __restrict__ Wout,
                         uint4* __restrict__ AG, uint4* __restrict__ W0F,
                         uint4* __restrict__ W1F, uint4* __restrict__ W2F) {
    const int gid = blockIdx.x * 256 + threadIdx.x;
    if (gid < 20480) {
        const int l = gid & 63;
        const int r2 = gid >> 6;
        const int fid = r2 % 20;
        const int jt = (r2 / 20) & 3;
        const int n = r2 / 80;
        const int s = fid & 1;
        const int gk = fid >> 1;
        int g, kq;
        if (gk < 9) { g = gk / 3; kq = gk % 3; } else { g = 3; kq = 2; }
        const int j = jt * 16 + (l & 15);
        const int lk = (l >> 4) & 3;
        const float scale = (g < 2) ? SC1 : SC2;
        uint wds[4];
        for (int i = 0; i < 4; ++i) {
            uint pk = 0;
            for (int hf = 0; hf < 2; ++hf) {
                const int e = 2 * i + hf;
                const int k = kq * 32 + 8 * lk + e;
                float v = 0.f;
                if (g < 3) {
                    if (k < 64)       v = Wh[(size_t)(n * 64 + k) * 192 + g * 64 + j];
                    else if (k < 72)  { if (g < 2) v = Wi[(size_t)(n * 8 + (k - 64)) * 192 + g * 64 + j]; }
                    else if (k == 72) v = bh[n * 192 + g * 64 + j];
                } else {
                    if (k >= 64 && k < 72) v = Wi[(size_t)(n * 8 + (k - 64)) * 192 + 128 + j];
                }
                v *= scale;
                ushort hi, lo; fsplit(v, hi, lo);
                pk |= ((uint)(s ? lo : hi)) << (16 * hf);
            }
            wds[i] = pk;
        }
        uint4 u; u.x = wds[0]; u.y = wds[1]; u.z = wds[2]; u.w = wds[3];
        AG[gid] = u;
    } else if (gid < 33024) {
        int id; const float* W; uint4* dst; int Nreal;
        if (gid < 28672)      { id = gid - 20480; W = W0;   dst = W0F; Nreal = 256; }
        else if (gid < 32768) { id = gid - 28672; W = W1;   dst = W1F; Nreal = 128; }
        else                  { id = gid - 32768; W = Wout; dst = W2F; Nreal = 8;   }
        const int l = id & 63;
        const int rr = id >> 6;
        const int kq = rr & 7;
        const int nt = rr >> 3;
        const int o = nt * 16 + (l & 15);
        const int lk = (l >> 4) & 3;
        uint wds[4];
        for (int i = 0; i < 4; ++i) {
            uint pk = 0;
            for (int hf = 0; hf < 2; ++hf) {
                const int e = 2 * i + hf;
                const int k = kq * 32 + 8 * lk + e;
                float v = 0.f;
                if (o < Nreal) v = W[(size_t)k * Nreal + o];
                pk |= ((uint)f16b(v)) << (16 * hf);
            }
            wds[i] = pk;
        }
        uint4 u; u.x = wds[0]; u.y = wds[1]; u.z = wds[2]; u.w = wds[3];
        dst[id] = u;
    }
}

// ============================ GRU (fp16 MFMA, x2) ==========================
// A = weights split hi/lo (20 frags, VGPR/AGPR-resident); B = h/x single fp16
// plane in LDS [m][128 ushorts] (256B rows) + granule XOR swizzle ^(row&7).
// Wave w = j-tile; computes both 16-batch column tiles (nt). 40 MFMA/wave/step.
// 1 barrier/step, double-buffered. Bias row (k=72) pre-written in both bufs.
__global__ __launch_bounds__(256, 3)
void gru_kernel(const float* __restrict__ x, const uint4* __restrict__ AG,
                ushort* __restrict__ featH, ushort* __restrict__ featL) {
    __shared__ __align__(16) ushort Bs[2][32 * 128];   // 16 KB total
    const int tid = threadIdx.x;
    const int l = tid & 63;
    const int w = tid >> 6;        // wave = j-tile
    const int lrow = l & 15;
    const int lk = l >> 4;
    const int n = blockIdx.y;
    const int bg = blockIdx.x * 32;

    {   // zero both buffers (h(0)=0, pad granules stay 0)
        uint4 z = {0, 0, 0, 0};
        uint4* p = (uint4*)&Bs[0][0];
        for (int i = tid; i < 1024; i += 256) p[i] = z;
    }
    __syncthreads();

    // A-fragments: 10 combos x {hi,lo}
    half8 A[20];
    const uint4* __restrict__ ab = AG + (size_t)((n * 4 + w) * 20) * 64 + l;
#pragma unroll
    for (int f = 0; f < 20; ++f) { uint4 v = ab[f * 64]; A[f] = *(half8*)&v; }

    // x staging role (wave 0): m = tid>>1, half = tid&1, 4 floats -> uint2
    const int sm = tid >> 1, sh = tid & 1;
    const float* __restrict__ xs = x + (size_t)(bg + sm) * 640 + n * 8 + sh * 4;

    if (tid < 64) {   // stage x(0) into buf0 (granule-8 image)
        const float4 v = *(const float4*)xs;
        uint2 pk;
        pk.x = (uint)f16b(v.x) | ((uint)f16b(v.y) << 16);
        pk.y = (uint)f16b(v.z) | ((uint)f16b(v.w) << 16);
        *(uint2*)&Bs[0][sm * 128 + (8 ^ (sm & 7)) * 8 + sh * 4] = pk;
    }
    if (tid < 64) {   // bias 1.0 at k=72 (granule-9 image, slot 0), both buffers
        const int m = tid & 31, bu = tid >> 5;
        Bs[bu][m * 128 + (9 ^ (m & 7)) * 8] = (ushort)0x3C00;
    }
    __syncthreads();

    f32x4 hold[2];
#pragma unroll
    for (int nt = 0; nt < 2; ++nt)
#pragma unroll
        for (int r = 0; r < 4; ++r) hold[nt][r] = 0.f;

    for (int t = 0; t < TT; ++t) {
        const int p = t & 1;
        const ushort* __restrict__ BH = &Bs[p][0];
        ushort* __restrict__ WH = &Bs[p ^ 1][0];

        // prefetch x(t+1) (wave 0), hidden under the MFMA phase
        float4 xv = {0.f, 0.f, 0.f, 0.f};
        if (tid < 64 && t < TT - 1) xv = *(const float4*)(xs + (t + 1) * 32);

        f32x4 acc[2][4];
#pragma unroll
        for (int nt = 0; nt < 2; ++nt)
#pragma unroll
            for (int g = 0; g < 4; ++g)
#pragma unroll
                for (int r = 0; r < 4; ++r) acc[nt][g][r] = 0.f;

#pragma unroll
        for (int nt = 0; nt < 2; ++nt) {
            const int rbase = (nt * 16 + lrow) * 128;
            const int key = lrow & 7;
#pragma unroll
            for (int kq = 0; kq < 3; ++kq) {
                const half8 bf = *(const half8*)&BH[rbase + ((kq * 4 + lk) ^ key) * 8];
#pragma unroll
                for (int g = 0; g < 3; ++g) {
                    acc[nt][g] = __builtin_amdgcn_mfma_f32_16x16x32_f16(A[(g * 3 + kq) * 2 + 0], bf, acc[nt][g], 0, 0, 0);
                    acc[nt][g] = __builtin_amdgcn_mfma_f32_16x16x32_f16(A[(g * 3 + kq) * 2 + 1], bf, acc[nt][g], 0, 0, 0);
                }
                if (kq == 2) {
                    acc[nt][3] = __builtin_amdgcn_mfma_f32_16x16x32_f16(A[18], bf, acc[nt][3], 0, 0, 0);
                    acc[nt][3] = __builtin_amdgcn_mfma_f32_16x16x32_f16(A[19], bf, acc[nt][3], 0, 0, 0);
                }
            }
        }

        // epilogue: accs pre-scaled -> sigmoid/tanh = rcp(1+exp2(.))
#pragma unroll
        for (int nt = 0; nt < 2; ++nt) {
            ushort hq[4];
#pragma unroll
            for (int r = 0; r < 4; ++r) {
                const float rg = __builtin_amdgcn_rcpf(1.f + __builtin_amdgcn_exp2f(acc[nt][0][r]));
                const float zg = __builtin_amdgcn_rcpf(1.f + __builtin_amdgcn_exp2f(acc[nt][1][r]));
                const float sarg = fmaf(rg, acc[nt][2][r], acc[nt][3][r]);
                const float sg = __builtin_amdgcn_rcpf(1.f + __builtin_amdgcn_exp2f(sarg));
                const float ng = fmaf(2.f, sg, -1.f);
                const float hv = fmaf(zg, hold[nt][r] - ng, ng);
                hold[nt][r] = hv;
                hq[r] = f16b(hv);
            }
            if (t < TT - 1) {   // j = w*16 + lk*4 + r  ->  granule w*2+(lk>>1)
                const int gsw = (w * 2 + (lk >> 1)) ^ (lrow & 7);
                uint2 pk;
                pk.x = (uint)hq[0] | ((uint)hq[1] << 16);
                pk.y = (uint)hq[2] | ((uint)hq[3] << 16);
                *(uint2*)&WH[(nt * 16 + lrow) * 128 + gsw * 8 + 4 * (lk & 1)] = pk;
            }
        }
        if (tid < 64 && t < TT - 1) {
            uint2 pk;
            pk.x = (uint)f16b(xv.x) | ((uint)f16b(xv.y) << 16);
            pk.y = (uint)f16b(xv.z) | ((uint)f16b(xv.w) << 16);
            *(uint2*)&WH[sm * 128 + (8 ^ (sm & 7)) * 8 + sh * 4] = pk;
        }
        __syncthreads();
    }

    // feat as fp16 hi/lo planes [B][256] (keeps MLP error budget unchanged)
#pragma unroll
    for (int nt = 0; nt < 2; ++nt) {
        ushort fh[4], fl[4];
#pragma unroll
        for (int r = 0; r < 4; ++r) fsplit(hold[nt][r], fh[r], fl[r]);
        uint2 ph, pl;
        ph.x = (uint)fh[0] | ((uint)fh[1] << 16);
        ph.y = (uint)fh[2] | ((uint)fh[3] << 16);
        pl.x = (uint)fl[0] | ((uint)fl[1] << 16);
        pl.y = (uint)fl[2] | ((uint)fl[3] << 16);
        const size_t fo = (size_t)(bg + nt * 16 + lrow) * 256 + n * 64 + w * 16 + 4 * lk;
        *(uint2*)&featH[fo] = ph;
        *(uint2*)&featL[fo] = pl;
    }
}

// ============================ MLP (fp16 MFMA, x2) — unchanged ==============
__global__ __launch_bounds__(256, 3)
void mlp_kernel(const ushort* __restrict__ featH, const ushort* __restrict__ featL,
                const uint4* __restrict__ W0F, const uint4* __restrict__ W1F,
                const uint4* __restrict__ W2F, const float* __restrict__ b0,
                const float* __restrict__ b1, const float* __restrict__ bout,
                float* __restrict__ out) {
    __shared__ __align__(16) ushort s1[2][32 * 256];
    __shared__ __align__(16) ushort s2[2][32 * 128];
    const int tid = threadIdx.x;
    const int l = tid & 63;
    const int w = tid >> 6;
    const int lrow = l & 15;
    const int lk = l >> 4;
    const int bg = blockIdx.x * 32;

    // ---- L0: feat[32,256] @ W0[256,256] ----
    f32x4 a0[2][4];
#pragma unroll
    for (int bt = 0; bt < 2; ++bt)
#pragma unroll
        for (int q = 0; q < 4; ++q)
#pragma unroll
            for (int r = 0; r < 4; ++r) a0[bt][q][r] = 0.f;

#pragma unroll 2
    for (int kq = 0; kq < 8; ++kq) {
        half8 aH[2], aL[2];
#pragma unroll
        for (int bt = 0; bt < 2; ++bt) {
            const size_t off = (size_t)(bg + bt * 16 + lrow) * 256 + kq * 32 + 8 * lk;
            aH[bt] = *(const half8*)&featH[off];
            aL[bt] = *(const half8*)&featL[off];
        }
#pragma unroll
        for (int q = 0; q < 4; ++q) {
            const uint4 bv = W0F[((w * 4 + q) * 8 + kq) * 64 + l];
            const half8 bw = *(const half8*)&bv;
#pragma unroll
            for (int bt = 0; bt < 2; ++bt) {
                a0[bt][q] = __builtin_amdgcn_mfma_f32_16x16x32_f16(aH[bt], bw, a0[bt][q], 0, 0, 0);
                a0[bt][q] = __builtin_amdgcn_mfma_f32_16x16x32_f16(aL[bt], bw, a0[bt][q], 0, 0, 0);
            }
        }
    }
#pragma unroll
    for (int bt = 0; bt < 2; ++bt)
#pragma unroll
        for (int q = 0; q < 4; ++q) {
            const int nn = (w * 4 + q) * 16 + lrow;
            const float bias = b0[nn];
            const int gc = nn >> 3, sub = nn & 7;
#pragma unroll
            for (int r = 0; r < 4; ++r) {
                const int row = bt * 16 + 4 * lk + r;
                float v = a0[bt][q][r] + bias;
                v = v > 0.f ? v : 0.f;
                ushort hi, lo; fsplit(v, hi, lo);
                const int gsw = gc ^ (row & 7);
                s1[0][row * 256 + gsw * 8 + sub] = hi;
                s1[1][row * 256 + gsw * 8 + sub] = lo;
            }
        }
    __syncthreads();

    // ---- L1: h1[32,256] @ W1[256,128] ----
    f32x4 a1[2][2];
#pragma unroll
    for (int bt = 0; bt < 2; ++bt)
#pragma unroll
        for (int u = 0; u < 2; ++u)
#pragma unroll
            for (int r = 0; r < 4; ++r) a1[bt][u][r] = 0.f;

#pragma unroll 2
    for (int kq = 0; kq < 8; ++kq) {
        half8 aH[2], aL[2];
#pragma unroll
        for (int bt = 0; bt < 2; ++bt) {
            const int row = bt * 16 + lrow;
            const int gsw = (kq * 4 + lk) ^ (row & 7);
            aH[bt] = *(const half8*)&s1[0][row * 256 + gsw * 8];
            aL[bt] = *(const half8*)&s1[1][row * 256 + gsw * 8];
        }
#pragma unroll
        for (int u = 0; u < 2; ++u) {
            const uint4 bv = W1F[((w + 4 * u) * 8 + kq) * 64 + l];
            const half8 bw = *(const half8*)&bv;
#pragma unroll
            for (int bt = 0; bt < 2; ++bt) {
                a1[bt][u] = __builtin_amdgcn_mfma_f32_16x16x32_f16(aH[bt], bw, a1[bt][u], 0, 0, 0);
                a1[bt][u] = __builtin_amdgcn_mfma_f32_16x16x32_f16(aL[bt], bw, a1[bt][u], 0, 0, 0);
            }
        }
    }
#pragma unroll
    for (int bt = 0; bt < 2; ++bt)
#pragma unroll
        for (int u = 0; u < 2; ++u) {
            const int nn = (w + 4 * u) * 16 + lrow;
            const float bias = b1[nn];
            const int gc = nn >> 3, sub = nn & 7;
#pragma unroll
            for (int r = 0; r < 4; ++r) {
                const int row = bt * 16 + 4 * lk + r;
                float v = a1[bt][u][r] + bias;
                v = v > 0.f ? v : 0.f;
                ushort hi, lo; fsplit(v, hi, lo);
                const int gsw = gc ^ (row & 7);
                s2[0][row * 128 + gsw * 8 + sub] = hi;
                s2[1][row * 128 + gsw * 8 + sub] = lo;
            }
        }
    __syncthreads();

    // ---- L2: h2[32,128] @ Wout[128,8->16pad], waves 0-1 ----
    if (w < 2) {
        const int bt = w;
        f32x4 a2;
#pragma unroll
        for (int r = 0; r < 4; ++r) a2[r] = 0.f;
#pragma unroll
        for (int kq = 0; kq < 4; ++kq) {
            const int row = bt * 16 + lrow;
            const int gsw = (kq * 4 + lk) ^ (row & 7);
            const half8 aH = *(const half8*)&s2[0][row * 128 + gsw * 8];
            const half8 aL = *(const half8*)&s2[1][row * 128 + gsw * 8];
            const uint4 bv = W2F[kq * 64 + l];
            const half8 bw = *(const half8*)&bv;
            a2 = __builtin_amdgcn_mfma_f32_16x16x32_f16(aH, bw, a2, 0, 0, 0);
            a2 = __builtin_amdgcn_mfma_f32_16x16x32_f16(aL, bw, a2, 0, 0, 0);
        }
        if (lrow < 8) {
            const float bo = bout[lrow];
#pragma unroll
            for (int r = 0; r < 4; ++r)
                out[(size_t)(bg + bt * 16 + 4 * lk + r) * 8 + lrow] = a2[r] + bo;
        }
    }
}

extern "C" void kernel_launch(void* const* d_in, const int* in_sizes, int n_in,
                              void* d_out, int out_size, void* d_ws, size_t ws_size,
                              hipStream_t stream) {
    const float* x    = (const float*)d_in[0];
    const float* Wi   = (const float*)d_in[1];
    const float* Wh   = (const float*)d_in[2];
    const float* bh   = (const float*)d_in[3];
    const float* W0   = (const float*)d_in[4];
    const float* b0   = (const float*)d_in[5];
    const float* W1   = (const float*)d_in[6];
    const float* b1   = (const float*)d_in[7];
    const float* Wout = (const float*)d_in[8];
    const float* bout = (const float*)d_in[9];

    char* wsb = (char*)d_ws;
    ushort* featH = (ushort*)wsb;                                   // 16 MB
    ushort* featL = (ushort*)(wsb + 16777216);                      // 16 MB
    uint4* AG  = (uint4*)(wsb + 33554432);                          // 327680 B
    uint4* W0F = (uint4*)(wsb + 33554432 + 327680);                 // 131072 B
    uint4* W1F = (uint4*)(wsb + 33554432 + 327680 + 131072);        // 65536 B
    uint4* W2F = (uint4*)(wsb + 33554432 + 327680 + 131072 + 65536);// 4096 B

    prep_all<<<129, 256, 0, stream>>>(Wh, Wi, bh, W0, W1, Wout, AG, W0F, W1F, W2F);
    gru_kernel<<<dim3(BT / 32, NA), 256, 0, stream>>>(x, AG, featH, featL);
    mlp_kernel<<<BT / 32, 256, 0, stream>>>(featH, featL, W0F, W1F, W2F, b0, b1, bout, (float*)d_out);
}